// Round 6
// baseline (219.944 us; speedup 1.0000x reference)
//
#include <hip/hip_runtime.h>

// Haar forward: input (B=8, C=64, H=512, W=512) fp32 NCHW
// output (B, 4*C, 256, 256), subband-major.
// Per 2x2 block {a,b,c,d}: LL=.25(a+b+c+d), k1=.25(a-b+c-d), k2=.25(a+b-c-d), k3=.25(a-b-c+d)
//
// R6 = R4 structure (best: 192 us) with ONE change: loads are REGULAR
// (cache-allocating) while stores stay non-temporal.
// Rationale: lane stride is 32 B with 16 B used per load instruction, so each
// of r0a/r0b touches every 64-B HBM sector of a 2-KiB span at half density.
// Regular loads let the complementary halves hit L1/L2; nt stores still
// stream past L2 (R4's proven win). A/B isolates nt-load over-fetch.

constexpr int B  = 8;
constexpr int C  = 64;
constexpr int H  = 512;
constexpr int W  = 512;
constexpr int HO = H / 2;   // 256
constexpr int WO = W / 2;   // 256
constexpr int W4 = WO / 4;  // 64 float4-chunks per output row

typedef float f32x4 __attribute__((ext_vector_type(4)));

__global__ __launch_bounds__(256) void haar_fwd(const float* __restrict__ x,
                                                float* __restrict__ y) {
    const int total = B * C * HO * W4;
    int idx = blockIdx.x * blockDim.x + threadIdx.x;
    if (idx >= total) return;

    const int j4 = idx & (W4 - 1);          // 0..63
    const int i  = (idx >> 6) & (HO - 1);   // 0..255
    const int m  = idx >> 14;               // image = b*C + c (0..511)

    const float* r0 = x + ((size_t)m * H + 2 * (size_t)i) * W + 8 * (size_t)j4;
    const float* r1 = r0 + W;
    const f32x4 r0a = *reinterpret_cast<const f32x4*>(r0);
    const f32x4 r0b = *reinterpret_cast<const f32x4*>(r0 + 4);
    const f32x4 r1a = *reinterpret_cast<const f32x4*>(r1);
    const f32x4 r1b = *reinterpret_cast<const f32x4*>(r1 + 4);

    // Pixel p: a=row0[2p], b=row0[2p+1], c=row1[2p], d=row1[2p+1]
    const float a0 = r0a.x, b0 = r0a.y, a1 = r0a.z, b1 = r0a.w;
    const float a2 = r0b.x, b2 = r0b.y, a3 = r0b.z, b3 = r0b.w;
    const float c0 = r1a.x, d0 = r1a.y, c1 = r1a.z, d1 = r1a.w;
    const float c2 = r1b.x, d2 = r1b.y, c3 = r1b.z, d3 = r1b.w;

    f32x4 ll, k1, k2, k3;
    ll.x = 0.25f * (a0 + b0 + c0 + d0);
    ll.y = 0.25f * (a1 + b1 + c1 + d1);
    ll.z = 0.25f * (a2 + b2 + c2 + d2);
    ll.w = 0.25f * (a3 + b3 + c3 + d3);

    k1.x = 0.25f * (a0 - b0 + c0 - d0);
    k1.y = 0.25f * (a1 - b1 + c1 - d1);
    k1.z = 0.25f * (a2 - b2 + c2 - d2);
    k1.w = 0.25f * (a3 - b3 + c3 - d3);

    k2.x = 0.25f * (a0 + b0 - c0 - d0);
    k2.y = 0.25f * (a1 + b1 - c1 - d1);
    k2.z = 0.25f * (a2 + b2 - c2 - d2);
    k2.w = 0.25f * (a3 + b3 - c3 - d3);

    k3.x = 0.25f * (a0 - b0 - c0 + d0);
    k3.y = 0.25f * (a1 - b1 - c1 + d1);
    k3.z = 0.25f * (a2 - b2 - c2 + d2);
    k3.w = 0.25f * (a3 - b3 - c3 + d3);

    const size_t plane  = (size_t)HO * WO;
    const size_t rowoff = (size_t)i * WO + 4 * (size_t)j4;
    float* yb = y + ((size_t)(m >> 6) * 4 * C + (m & (C - 1))) * plane + rowoff;

    __builtin_nontemporal_store(ll, reinterpret_cast<f32x4*>(yb));
    __builtin_nontemporal_store(k1, reinterpret_cast<f32x4*>(yb + (size_t)C * plane));
    __builtin_nontemporal_store(k2, reinterpret_cast<f32x4*>(yb + (size_t)2 * C * plane));
    __builtin_nontemporal_store(k3, reinterpret_cast<f32x4*>(yb + (size_t)3 * C * plane));
}

extern "C" void kernel_launch(void* const* d_in, const int* in_sizes, int n_in,
                              void* d_out, int out_size, void* d_ws, size_t ws_size,
                              hipStream_t stream) {
    const float* x = (const float*)d_in[0];
    float* y = (float*)d_out;

    const int total = B * C * HO * W4;   // 8,388,608 threads
    const int threads = 256;
    const int blocks = (total + threads - 1) / threads;   // 32768
    haar_fwd<<<blocks, threads, 0, stream>>>(x, y);
}